// Round 1
// baseline (677.041 us; speedup 1.0000x reference)
//
#include <hip/hip_runtime.h>

// FEM stiffness matvec: KU[n] += sum over elements e containing n of
// (rows of K[type(e)]) @ gather(U, nodIdx[e]).
//
// Round 0: one thread per element, global __restrict__ filter reads
// (64 x 24 x 24 fp32 = 147 KB, L2-resident), float4 row loads,
// atomicAdd scatter. Output zeroed via hipMemsetAsync (graph-capturable).

__global__ __launch_bounds__(256) void feconv_elem_kernel(
    const float* __restrict__ U,        // [N, 3]
    const float* __restrict__ K,        // [64, 24, 24]
    const int*   __restrict__ types,    // [E]
    const int*   __restrict__ nodIdx,   // [E, 8]
    float*       __restrict__ KU,       // [N, 3]
    int n_elems)
{
    int e = blockIdx.x * blockDim.x + threadIdx.x;
    if (e >= n_elems) return;

    int t = types[e];

    // 8 node indices: 32B-aligned, two int4 loads
    const int4* idx4 = (const int4*)(nodIdx + (size_t)e * 8);
    int4 iA = idx4[0];
    int4 iB = idx4[1];
    int nodes[8] = {iA.x, iA.y, iA.z, iA.w, iB.x, iB.y, iB.z, iB.w};

    // gather u_e [24]
    float ue[24];
#pragma unroll
    for (int j = 0; j < 8; ++j) {
        const float* up = U + (size_t)nodes[j] * 3;
        ue[3 * j + 0] = up[0];
        ue[3 * j + 1] = up[1];
        ue[3 * j + 2] = up[2];
    }

    // f_e = K_t @ u_e ; scatter-add each row result immediately
    const float* Kt = K + (size_t)t * 576;
#pragma unroll
    for (int i = 0; i < 24; ++i) {
        const float4* row = (const float4*)(Kt + i * 24);  // 96B row: 16B-aligned
        float acc = 0.f;
#pragma unroll
        for (int q = 0; q < 6; ++q) {
            float4 k = row[q];
            acc += k.x * ue[4 * q + 0] + k.y * ue[4 * q + 1]
                 + k.z * ue[4 * q + 2] + k.w * ue[4 * q + 3];
        }
        atomicAdd(&KU[(size_t)nodes[i / 3] * 3 + (i % 3)], acc);
    }
}

extern "C" void kernel_launch(void* const* d_in, const int* in_sizes, int n_in,
                              void* d_out, int out_size, void* d_ws, size_t ws_size,
                              hipStream_t stream) {
    const float* U      = (const float*)d_in[0];   // [N,3] fp32
    const float* K      = (const float*)d_in[1];   // [64,24,24] fp32
    const int*   types  = (const int*)d_in[2];     // [E] int32
    const int*   nodIdx = (const int*)d_in[3];     // [E,8] int32
    float*       KU     = (float*)d_out;           // [N,3] fp32

    int n_elems = in_sizes[2];

    // d_out is poisoned 0xAA before every timed launch — zero it.
    hipMemsetAsync(KU, 0, (size_t)out_size * sizeof(float), stream);

    int block = 256;
    int grid = (n_elems + block - 1) / block;
    feconv_elem_kernel<<<grid, block, 0, stream>>>(U, K, types, nodIdx, KU, n_elems);
}

// Round 2
// 674.817 us; speedup vs baseline: 1.0033x; 1.0033x over previous
//
#include <hip/hip_runtime.h>

// FEM stiffness matvec KU = sum_e scatter(K_type(e) @ gather(U, e)).
//
// Round 1: stage all 64 filter matrices (24x24 fp32 = 147 KB) in LDS.
// Rationale: types are random per lane, so global filter loads fan out to
// ~64 L2 requests per instruction (~18M scattered reqs total). LDS serves
// divergent per-lane addresses natively. Per-type stride padded to 577
// floats (577 % 32 == 1) so lanes with random t spread across all 32 banks
// (~2-way avg aliasing = free). Block=1024, 1 block/CU (LDS-limited),
// grid=256, grid-stride loop => 16 waves/CU, same occupancy as round 0.

#define TPB      1024
#define NTYPES   64
#define KSIZE    576            // 24*24
#define KSTRIDE  577            // +1 pad: breaks bank-conflict on random t

__global__ __launch_bounds__(TPB, 1) void feconv_lds_kernel(
    const float* __restrict__ U,        // [N, 3]
    const float* __restrict__ K,        // [64, 24, 24]
    const int*   __restrict__ types,    // [E]
    const int*   __restrict__ nodIdx,   // [E, 8]
    float*       __restrict__ KU,       // [N, 3]
    int n_elems)
{
    extern __shared__ float sK[];       // NTYPES * KSTRIDE floats = 147,712 B

    // Cooperative fill: coalesced global read, padded LDS write.
    for (int r = threadIdx.x; r < NTYPES * KSIZE; r += TPB) {
        int t = r / KSIZE;
        int c = r - t * KSIZE;
        sK[t * KSTRIDE + c] = K[r];
    }
    __syncthreads();

    int stride = gridDim.x * blockDim.x;
    for (int e = blockIdx.x * blockDim.x + threadIdx.x; e < n_elems; e += stride) {
        int t = types[e];

        const int4* idx4 = (const int4*)(nodIdx + (size_t)e * 8);
        int4 iA = idx4[0];
        int4 iB = idx4[1];
        int nodes[8] = {iA.x, iA.y, iA.z, iA.w, iB.x, iB.y, iB.z, iB.w};

        // gather u_e [24] (12 B per node, scattered)
        float ue[24];
#pragma unroll
        for (int j = 0; j < 8; ++j) {
            const float* up = U + (size_t)nodes[j] * 3;
            ue[3 * j + 0] = up[0];
            ue[3 * j + 1] = up[1];
            ue[3 * j + 2] = up[2];
        }

        // f_e = K_t @ u_e from LDS; scatter-add each row result
        const float* Kt = &sK[t * KSTRIDE];
#pragma unroll
        for (int i = 0; i < 24; ++i) {
            float acc = 0.f;
#pragma unroll
            for (int j = 0; j < 24; ++j) {
                acc += Kt[24 * i + j] * ue[j];
            }
            atomicAdd(&KU[(size_t)nodes[i / 3] * 3 + (i % 3)], acc);
        }
    }
}

extern "C" void kernel_launch(void* const* d_in, const int* in_sizes, int n_in,
                              void* d_out, int out_size, void* d_ws, size_t ws_size,
                              hipStream_t stream) {
    const float* U      = (const float*)d_in[0];   // [N,3] fp32
    const float* K      = (const float*)d_in[1];   // [64,24,24] fp32
    const int*   types  = (const int*)d_in[2];     // [E] int32
    const int*   nodIdx = (const int*)d_in[3];     // [E,8] int32
    float*       KU     = (float*)d_out;           // [N,3] fp32

    int n_elems = in_sizes[2];

    // d_out is poisoned 0xAA before every timed launch — zero it.
    hipMemsetAsync(KU, 0, (size_t)out_size * sizeof(float), stream);

    size_t lds_bytes = (size_t)NTYPES * KSTRIDE * sizeof(float);  // 147,712
    int grid = 256;  // 1 block/CU (LDS-limited); grid-stride covers E
    feconv_lds_kernel<<<grid, TPB, lds_bytes, stream>>>(U, K, types, nodIdx, KU, n_elems);
}

// Round 3
// 326.563 us; speedup vs baseline: 2.0732x; 2.0664x over previous
//
#include <hip/hip_runtime.h>

// FEM stiffness matvec KU = sum_e scatter(K_type(e) @ gather(U, e)).
//
// Round 2: eliminate the 12M scattered device-scope fp32 atomics (measured
// as 375 MB of ~32B write-through transactions = the random-transaction
// wall at ~25 G trans/s). Two-phase:
//   K1: per element, compute the 8 per-node force triples and append 16 B
//       records {node, fx, fy, fz} into per-node-range buckets (4096 nodes
//       per bucket, 245 buckets). Tail reservation is block-aggregated in
//       LDS, so global atomics drop from 4M to ~120K (on 245 counters).
//   K2: one block per bucket; accumulate records into a 48 KB LDS dense
//       accumulator with LDS ds_add_f32 atomics; write KU coalesced.
// Bucket cap 20480 vs mean 16384 (sigma~128): overflow "impossible", but a
// correctness fallback (direct atomicAdd into KU) handles it anyway.
// If ws_size is too small for the 80 MB record buffer, fall back to the
// round-0 single-kernel atomic version (branch on ws_size is call-invariant
// => graph-capture safe).

#define K1_TPB   256
#define EPT      4
#define CHUNK    (K1_TPB * EPT)     // 1024 elements per block
#define RSHIFT   12
#define RNODES   4096               // nodes per bucket (1 << RSHIFT)
#define MAXB     256                // supports up to 1,048,576 nodes
#define CAP      20480              // record slots per bucket
#define K2_TPB   1024

__global__ __launch_bounds__(K1_TPB) void feconv_bin_kernel(
    const float* __restrict__ U,        // [N, 3]
    const float* __restrict__ K,        // [64, 24, 24]
    const int*   __restrict__ types,    // [E]
    const int*   __restrict__ nodIdx,   // [E, 8]
    float*       __restrict__ KU,       // [N, 3] (overflow fallback only)
    unsigned*    __restrict__ tails,    // [n_buckets]
    uint4*       __restrict__ recs,     // [n_buckets * CAP]
    int n_elems, int n_buckets)
{
    __shared__ unsigned sCnt[MAXB];
    __shared__ unsigned sBase[MAXB];

    for (int i = threadIdx.x; i < n_buckets; i += K1_TPB) sCnt[i] = 0;
    __syncthreads();

    const int e0 = blockIdx.x * CHUNK + threadIdx.x;
    int nodes[EPT][8];
    int tt[EPT];

    // pass A: load connectivity, count bucket usage for this block
#pragma unroll
    for (int k = 0; k < EPT; ++k) {
        int e = e0 + k * K1_TPB;
        if (e < n_elems) {
            tt[k] = types[e];
            const int4* p = (const int4*)(nodIdx + (size_t)e * 8);
            int4 a = p[0], b = p[1];
            nodes[k][0] = a.x; nodes[k][1] = a.y; nodes[k][2] = a.z; nodes[k][3] = a.w;
            nodes[k][4] = b.x; nodes[k][5] = b.y; nodes[k][6] = b.z; nodes[k][7] = b.w;
#pragma unroll
            for (int j = 0; j < 8; ++j)
                atomicAdd(&sCnt[(unsigned)nodes[k][j] >> RSHIFT], 1u);
        }
    }
    __syncthreads();

    // pass B: one global tail reservation per (block, bucket)
    for (int b = threadIdx.x; b < n_buckets; b += K1_TPB) {
        unsigned c = sCnt[b];
        sBase[b] = c ? atomicAdd(&tails[b], c) : 0u;
        sCnt[b] = 0;                     // reuse as local cursor
    }
    __syncthreads();

    // pass C: gather u_e, compute 3-row force triples, write records
#pragma unroll
    for (int k = 0; k < EPT; ++k) {
        int e = e0 + k * K1_TPB;
        if (e >= n_elems) continue;

        float ue[24];
#pragma unroll
        for (int j = 0; j < 8; ++j) {
            const float* up = U + (size_t)nodes[k][j] * 3;
            ue[3 * j + 0] = up[0];
            ue[3 * j + 1] = up[1];
            ue[3 * j + 2] = up[2];
        }

        const float* Kt = K + (size_t)tt[k] * 576;
#pragma unroll
        for (int j = 0; j < 8; ++j) {
            const float4* r0 = (const float4*)(Kt + (3 * j + 0) * 24);
            const float4* r1 = (const float4*)(Kt + (3 * j + 1) * 24);
            const float4* r2 = (const float4*)(Kt + (3 * j + 2) * 24);
            float a0 = 0.f, a1 = 0.f, a2 = 0.f;
#pragma unroll
            for (int q = 0; q < 6; ++q) {
                float4 k0 = r0[q], k1 = r1[q], k2 = r2[q];
                float u0 = ue[4 * q + 0], u1 = ue[4 * q + 1];
                float u2 = ue[4 * q + 2], u3 = ue[4 * q + 3];
                a0 += k0.x * u0 + k0.y * u1 + k0.z * u2 + k0.w * u3;
                a1 += k1.x * u0 + k1.y * u1 + k1.z * u2 + k1.w * u3;
                a2 += k2.x * u0 + k2.y * u1 + k2.z * u2 + k2.w * u3;
            }
            unsigned n = (unsigned)nodes[k][j];
            unsigned b = n >> RSHIFT;
            unsigned pos = sBase[b] + atomicAdd(&sCnt[b], 1u);
            if (pos < CAP) {
                recs[(size_t)b * CAP + pos] =
                    make_uint4(n, __float_as_uint(a0), __float_as_uint(a1),
                               __float_as_uint(a2));
            } else {  // statistically unreachable; keeps correctness absolute
                atomicAdd(&KU[(size_t)n * 3 + 0], a0);
                atomicAdd(&KU[(size_t)n * 3 + 1], a1);
                atomicAdd(&KU[(size_t)n * 3 + 2], a2);
            }
        }
    }
}

__global__ __launch_bounds__(K2_TPB, 1) void feconv_acc_kernel(
    const uint4*    __restrict__ recs,
    const unsigned* __restrict__ tails,
    float*          __restrict__ KU,     // [N, 3], pre-zeroed (+= for overflow path)
    int n_nodes)
{
    __shared__ float sAcc[RNODES * 3];   // 48 KB
    const int b = blockIdx.x;

    for (int i = threadIdx.x; i < RNODES * 3; i += K2_TPB) sAcc[i] = 0.f;
    __syncthreads();

    unsigned cnt = tails[b];
    if (cnt > CAP) cnt = CAP;
    const uint4* base = recs + (size_t)b * CAP;
    for (unsigned i = threadIdx.x; i < cnt; i += K2_TPB) {
        uint4 r = base[i];
        unsigned local = (r.x & (RNODES - 1)) * 3;
        atomicAdd(&sAcc[local + 0], __uint_as_float(r.y));  // ds_add_f32
        atomicAdd(&sAcc[local + 1], __uint_as_float(r.z));
        atomicAdd(&sAcc[local + 2], __uint_as_float(r.w));
    }
    __syncthreads();

    const int nbase = b * RNODES;
    int limit = n_nodes - nbase;
    if (limit > RNODES) limit = RNODES;
    limit *= 3;
    float* out = KU + (size_t)nbase * 3;
    for (int i = threadIdx.x; i < limit; i += K2_TPB) out[i] += sAcc[i];
}

// ---- fallback (round-0 style) if ws_size can't hold the record buffer ----
__global__ __launch_bounds__(256) void feconv_elem_kernel(
    const float* __restrict__ U, const float* __restrict__ K,
    const int* __restrict__ types, const int* __restrict__ nodIdx,
    float* __restrict__ KU, int n_elems)
{
    int e = blockIdx.x * blockDim.x + threadIdx.x;
    if (e >= n_elems) return;
    int t = types[e];
    const int4* idx4 = (const int4*)(nodIdx + (size_t)e * 8);
    int4 iA = idx4[0], iB = idx4[1];
    int nodes[8] = {iA.x, iA.y, iA.z, iA.w, iB.x, iB.y, iB.z, iB.w};
    float ue[24];
#pragma unroll
    for (int j = 0; j < 8; ++j) {
        const float* up = U + (size_t)nodes[j] * 3;
        ue[3 * j + 0] = up[0]; ue[3 * j + 1] = up[1]; ue[3 * j + 2] = up[2];
    }
    const float* Kt = K + (size_t)t * 576;
#pragma unroll
    for (int i = 0; i < 24; ++i) {
        const float4* row = (const float4*)(Kt + i * 24);
        float acc = 0.f;
#pragma unroll
        for (int q = 0; q < 6; ++q) {
            float4 k = row[q];
            acc += k.x * ue[4 * q + 0] + k.y * ue[4 * q + 1]
                 + k.z * ue[4 * q + 2] + k.w * ue[4 * q + 3];
        }
        atomicAdd(&KU[(size_t)nodes[i / 3] * 3 + (i % 3)], acc);
    }
}

extern "C" void kernel_launch(void* const* d_in, const int* in_sizes, int n_in,
                              void* d_out, int out_size, void* d_ws, size_t ws_size,
                              hipStream_t stream) {
    const float* U      = (const float*)d_in[0];
    const float* Kf     = (const float*)d_in[1];
    const int*   types  = (const int*)d_in[2];
    const int*   nodIdx = (const int*)d_in[3];
    float*       KU     = (float*)d_out;

    const int n_elems = in_sizes[2];
    const int n_nodes = in_sizes[0] / 3;
    const int n_buckets = (n_nodes + RNODES - 1) / RNODES;   // 245 for N=1M

    hipMemsetAsync(KU, 0, (size_t)out_size * sizeof(float), stream);

    const size_t rec_off = 4096;
    const size_t need = rec_off + (size_t)n_buckets * CAP * sizeof(uint4);

    if (n_buckets <= MAXB && ws_size >= need) {
        unsigned* tails = (unsigned*)d_ws;
        uint4*    recs  = (uint4*)((char*)d_ws + rec_off);
        hipMemsetAsync(tails, 0, n_buckets * sizeof(unsigned), stream);

        int grid1 = (n_elems + CHUNK - 1) / CHUNK;
        feconv_bin_kernel<<<grid1, K1_TPB, 0, stream>>>(
            U, Kf, types, nodIdx, KU, tails, recs, n_elems, n_buckets);
        feconv_acc_kernel<<<n_buckets, K2_TPB, 0, stream>>>(
            recs, tails, KU, n_nodes);
    } else {
        int block = 256;
        int grid = (n_elems + block - 1) / block;
        feconv_elem_kernel<<<grid, block, 0, stream>>>(
            U, Kf, types, nodIdx, KU, n_elems);
    }
}